// Round 1
// baseline (179.701 us; speedup 1.0000x reference)
//
#include <hip/hip_runtime.h>

#define D_ 64
#define L_ 50
#define B_ 4096
#define T_ 100
#define SP 65    // f32 gi buffer stride
#define RS 72    // bf16 eb row stride (144 B, 16B-aligned for b128)

typedef __attribute__((ext_vector_type(8))) short  short8;   // 8 bf16 = 4 VGPRs
typedef __attribute__((ext_vector_type(4))) float  float4v;  // MFMA acc
typedef __attribute__((ext_vector_type(4))) unsigned short ushort4v;

__device__ __forceinline__ float sigmoidf_(float x) {
    return 1.0f / (1.0f + __expf(-x));
}
__device__ __forceinline__ unsigned short f2bf(float x) {   // RNE f32->bf16
    unsigned u = __builtin_bit_cast(unsigned, x);
    return (unsigned short)((u + 0x7fffu + ((u >> 16) & 1u)) >> 16);
}
__device__ __forceinline__ float bf2f(unsigned short s) {
    return __builtin_bit_cast(float, (unsigned)s << 16);
}

// Prelude (runs once per launch, ~16 KB): wbT[c*64+k] = bf16(W[k][c])
__global__ __launch_bounds__(256) void hgn_transpose_w(
    const float* __restrict__ fg_item_W, unsigned short* __restrict__ wbT)
{
    const int i = blockIdx.x * 256 + threadIdx.x;   // i over 4096
    const int k = i >> 6, c = i & 63;
    wbT[c * 64 + k] = f2bf(fg_item_W[i]);           // coalesced read, scattered write
}

// Main: one block (4 waves) per batch b.
__global__ __launch_bounds__(256) void hgn_fused_kernel(
    const int* __restrict__ item_seq,          // [B,L]
    const int* __restrict__ user_ids,          // [B]
    const int* __restrict__ items_to_predict,  // [B,T]
    const float* __restrict__ user_emb_table,  // [U,D]
    const float* __restrict__ item_emb_table,  // [I,D]
    const unsigned short* __restrict__ wbT,    // [64,64] bf16 W^T (precomputed)
    const float* __restrict__ fg_item_b,       // [D]
    const float* __restrict__ fg_user_W,       // [D,D]
    const float* __restrict__ fg_user_b,       // [D]
    const float* __restrict__ ig_item,         // [D]
    const float* __restrict__ ig_user,         // [D,L]
    const float* __restrict__ W2,              // [I,D]
    const float* __restrict__ b2,              // [I]
    float* __restrict__ out)                   // [B,T]
{
    __shared__ unsigned short eb_sh[64 * RS];          // E rows bf16 (rows>=50 garbage, harmless)
    __shared__ float part_sh[L_ * SP];                 // gi
    __shared__ __align__(16) float u_sh[D_];
    __shared__ __align__(16) float v_sh[D_];
    __shared__ float gb_sh[D_];
    __shared__ float s_sh[L_];
    __shared__ float bp_sh[2][64];                     // B-phase d-half partials
    __shared__ float esum_sh[D_];
    __shared__ int   idx_sh[L_];

    const int t    = threadIdx.x;
    const int lane = t & 63;
    const int wave = t >> 6;
    const int b    = blockIdx.x;

    if (t < L_) idx_sh[t] = item_seq[b * L_ + t];
    if (t >= 64 && t < 128) {
        const int uid = user_ids[b];
        u_sh[t - 64] = user_emb_table[(size_t)uid * D_ + (t - 64)];
    }
    __syncthreads();   // idx_sh / u_sh ready

    // ---- Prefetch phase-D W2 rows into registers NOW. The addresses depend
    // only on items_to_predict, so the gather latency overlaps the E-staging
    // gathers below and drains at the same (pre-existing) barrier. This
    // removes the end-of-chain exposed latency that dominated phase D.
    // 2 threads per t-row, 8 float4 each = 32 VGPRs held across the kernel.
    float4 wpre[8];
    float  b2pre = 0.f;
    if (t < 2 * T_) {
        const int tt = t >> 1, half = t & 1;
        const int idx = items_to_predict[b * T_ + tt];
        const float4* wrow = (const float4*)(W2 + (size_t)idx * D_ + half * 32);
#pragma unroll
        for (int kk = 0; kk < 8; ++kk) wpre[kk] = wrow[kk];
        if (half == 0) b2pre = b2[idx];
    }

    if (wave == 3) {
        // gbias[d] = fg_item_b + fg_user_b + u @ fg_user_W (coalesced, L1-hot)
        float g0 = fg_item_b[lane], g1 = fg_user_b[lane], g2 = 0.f, g3 = 0.f;
#pragma unroll
        for (int k = 0; k < D_; k += 4) {
            g0 = fmaf(u_sh[k + 0], fg_user_W[(k + 0) * D_ + lane], g0);
            g1 = fmaf(u_sh[k + 1], fg_user_W[(k + 1) * D_ + lane], g1);
            g2 = fmaf(u_sh[k + 2], fg_user_W[(k + 2) * D_ + lane], g2);
            g3 = fmaf(u_sh[k + 3], fg_user_W[(k + 3) * D_ + lane], g3);
        }
        gb_sh[lane] = (g0 + g1) + (g2 + g3);
    } else {
        // waves 0-2 (192 threads): stage E as bf16 (800 float4 gathers)
        for (int i = t; i < L_ * 16; i += 192) {
            const int l = i >> 4, qd = i & 15;
            const float4 r = ((const float4*)(item_emb_table + (size_t)idx_sh[l] * D_))[qd];
            ushort4v o = { f2bf(r.x), f2bf(r.y), f2bf(r.z), f2bf(r.w) };
            *(ushort4v*)&eb_sh[l * RS + qd * 4] = o;
        }
    }
    __syncthreads();   // eb / gb ready (W2 prefetch also drained here)

    // ---- MFMA gate matmul + fused finalize. Wave w -> P rows [16w,16w+16).
    {
        const int m = lane & 15, q = lane >> 4;
        const int arow = 16 * wave + m;
        const short8 a0 = *(const short8*)&eb_sh[arow * RS + q * 8];       // k 0..31
        const short8 a1 = *(const short8*)&eb_sh[arow * RS + 32 + q * 8];  // k 32..63
#pragma unroll
        for (int n = 0; n < 4; ++n) {
            const int col = 16 * n + m;
            const short8 b0 = *(const short8*)&wbT[col * 64 + q * 8];      // global, L1-hot
            const short8 b1 = *(const short8*)&wbT[col * 64 + 32 + q * 8];
            float4v acc = {0.f, 0.f, 0.f, 0.f};
            acc = __builtin_amdgcn_mfma_f32_16x16x32_bf16(a0, b0, acc, 0, 0, 0);
            acc = __builtin_amdgcn_mfma_f32_16x16x32_bf16(a1, b1, acc, 0, 0, 0);
            const float gbc = gb_sh[col];
#pragma unroll
            for (int r = 0; r < 4; ++r) {
                const int l = 16 * wave + q * 4 + r;   // C/D: row=q*4+r, col=16n+m
                if (l < L_) {
                    const float e = bf2f(eb_sh[l * RS + col]);
                    part_sh[l * SP + col] = e * sigmoidf_(acc[r] + gbc);
                }
            }
        }
    }
    __syncthreads();   // gi ready

    // ---- Phase B partials (waves 0,1: d-halves) + esum (wave 2)
    if (wave < 2) {
        if (lane < L_) {
            const int d0 = 32 * wave;
            float p0 = 0.f, p1 = 0.f, p2 = 0.f, p3 = 0.f;
#pragma unroll
            for (int j = 0; j < 32; j += 4) {
                const int d = d0 + j;
                p0 = fmaf(part_sh[lane * SP + d + 0], ig_item[d + 0], p0);
                p1 = fmaf(part_sh[lane * SP + d + 1], ig_item[d + 1], p1);
                p2 = fmaf(part_sh[lane * SP + d + 2], ig_item[d + 2], p2);
                p3 = fmaf(part_sh[lane * SP + d + 3], ig_item[d + 3], p3);
                p0 = fmaf(u_sh[d + 0], ig_user[(d + 0) * L_ + lane], p0);
                p1 = fmaf(u_sh[d + 1], ig_user[(d + 1) * L_ + lane], p1);
                p2 = fmaf(u_sh[d + 2], ig_user[(d + 2) * L_ + lane], p2);
                p3 = fmaf(u_sh[d + 3], ig_user[(d + 3) * L_ + lane], p3);
            }
            bp_sh[wave][lane] = (p0 + p1) + (p2 + p3);
        }
    } else if (wave == 2) {            // esum[d] = sum_l e[l][d]
        float e0 = 0.f, e1 = 0.f;
#pragma unroll
        for (int l = 0; l < L_; l += 2) {
            e0 += bf2f(eb_sh[l * RS + lane]);
            e1 += bf2f(eb_sh[(l + 1) * RS + lane]);
        }
        esum_sh[lane] = e0 + e1;
    }
    __syncthreads();   // bp / esum ready

    // ---- Phase C: wave 0: s = sigmoid(bp0+bp1); v = u + union/ssum + esum
    if (wave == 0) {
        if (lane < L_) s_sh[lane] = sigmoidf_(bp_sh[0][lane] + bp_sh[1][lane]);
        // same-wave LDS dependency -> lgkmcnt, no barrier
        float a0 = 0.f, a1 = 0.f, ss = 0.f;
        for (int l = 0; l < L_; l += 2) {
            const float sA = s_sh[l], sB = s_sh[l + 1];
            a0 = fmaf(part_sh[l * SP + lane], sA, a0);
            a1 = fmaf(part_sh[(l + 1) * SP + lane], sB, a1);
            ss += sA + sB;
        }
        v_sh[lane] = u_sh[lane] + (a0 + a1) / ss + esum_sh[lane];
    }
    __syncthreads();   // v_sh ready

    // ---- Phase D: 2 threads per (b,t); W2 already in registers (wpre),
    // so this is pure LDS+VALU: 32 FMA + one shfl.
    if (t < 2 * T_) {
        const int tt = t >> 1, half = t & 1;
        const float* vhalf = v_sh + half * 32;
        float r0 = 0.f, r1 = 0.f, r2 = 0.f, r3 = 0.f;
#pragma unroll
        for (int kk = 0; kk < 8; ++kk) {
            const float4 w4 = wpre[kk];
            const float4 v4 = ((const float4*)vhalf)[kk];
            r0 = fmaf(v4.x, w4.x, r0);
            r1 = fmaf(v4.y, w4.y, r1);
            r2 = fmaf(v4.z, w4.z, r2);
            r3 = fmaf(v4.w, w4.w, r3);
        }
        float r = (r0 + r1) + (r2 + r3);
        r += __shfl_xor(r, 1, 64);
        if (half == 0) out[b * T_ + tt] = r + b2pre;
    }
}

extern "C" void kernel_launch(void* const* d_in, const int* in_sizes, int n_in,
                              void* d_out, int out_size, void* d_ws, size_t ws_size,
                              hipStream_t stream) {
    const int*   item_seq   = (const int*)d_in[0];
    const int*   user_ids   = (const int*)d_in[1];
    const int*   items_pred = (const int*)d_in[2];
    const float* uet        = (const float*)d_in[3];
    const float* iet        = (const float*)d_in[4];
    const float* fgiW       = (const float*)d_in[5];
    const float* fgib       = (const float*)d_in[6];
    const float* fguW       = (const float*)d_in[7];
    const float* fgub       = (const float*)d_in[8];
    const float* igi        = (const float*)d_in[9];
    const float* igu        = (const float*)d_in[10];
    const float* W2         = (const float*)d_in[11];
    const float* b2t        = (const float*)d_in[12];

    unsigned short* wbT = (unsigned short*)d_ws;   // 8 KB bf16 W^T

    hgn_transpose_w<<<16, 256, 0, stream>>>(fgiW, wbT);
    hgn_fused_kernel<<<B_, 256, 0, stream>>>(
        item_seq, user_ids, items_pred, uet, iet,
        wbT, fgib, fguW, fgub, igi, igu, W2, b2t, (float*)d_out);
}

// Round 2
// 163.112 us; speedup vs baseline: 1.1017x; 1.1017x over previous
//
#include <hip/hip_runtime.h>

#define D_ 64
#define L_ 50
#define B_ 4096
#define T_ 100
#define SP2 66   // bf16 gi buffer stride (132 B: dword stride 33 -> conflict-free both axes)
#define RS 72    // bf16 eb row stride (144 B, 16B-aligned for b128)

typedef __attribute__((ext_vector_type(8))) short  short8;   // 8 bf16 = 4 VGPRs
typedef __attribute__((ext_vector_type(4))) float  float4v;  // MFMA acc
typedef __attribute__((ext_vector_type(4))) unsigned short ushort4v;

__device__ __forceinline__ float sigmoidf_(float x) {
    return 1.0f / (1.0f + __expf(-x));
}
__device__ __forceinline__ unsigned short f2bf(float x) {   // RNE f32->bf16
    unsigned u = __builtin_bit_cast(unsigned, x);
    return (unsigned short)((u + 0x7fffu + ((u >> 16) & 1u)) >> 16);
}
__device__ __forceinline__ float bf2f(unsigned short s) {
    return __builtin_bit_cast(float, (unsigned)s << 16);
}

// Prelude (runs once per launch, ~16 KB): wbT[c*64+k] = bf16(W[k][c])
__global__ __launch_bounds__(256) void hgn_transpose_w(
    const float* __restrict__ fg_item_W, unsigned short* __restrict__ wbT)
{
    const int i = blockIdx.x * 256 + threadIdx.x;   // i over 4096
    const int k = i >> 6, c = i & 63;
    wbT[c * 64 + k] = f2bf(fg_item_W[i]);           // coalesced read, scattered write
}

// Main: one block (4 waves) per batch b. VGPR must stay <= 64 (residency
// quantum halves past 64: measured round-1, 68 VGPR -> blocks/CU 6 -> 4).
__global__ __launch_bounds__(256) void hgn_fused_kernel(
    const int* __restrict__ item_seq,          // [B,L]
    const int* __restrict__ user_ids,          // [B]
    const int* __restrict__ items_to_predict,  // [B,T]
    const float* __restrict__ user_emb_table,  // [U,D]
    const float* __restrict__ item_emb_table,  // [I,D]
    const unsigned short* __restrict__ wbT,    // [64,64] bf16 W^T (precomputed)
    const float* __restrict__ fg_item_b,       // [D]
    const float* __restrict__ fg_user_W,       // [D,D]
    const float* __restrict__ fg_user_b,       // [D]
    const float* __restrict__ ig_item,         // [D]
    const float* __restrict__ ig_user,         // [D,L]
    const float* __restrict__ W2,              // [I,D]
    const float* __restrict__ b2,              // [I]
    float* __restrict__ out)                   // [B,T]
{
    // LDS diet: total ~17.8 KB -> 8 blocks/CU (was 24 KB -> 6 blocks/CU).
    __shared__ unsigned short eb_sh[64 * RS];            // 9216 B: E rows bf16
    __shared__ __align__(8) unsigned short part2_sh[L_ * SP2];  // 6600 B: gi bf16
    __shared__ __align__(16) float u_sh[D_];
    __shared__ __align__(16) float v_sh[D_];
    __shared__ float gb_sh[D_];
    __shared__ float s_sh[L_];
    __shared__ float bp_sh[2][64];                       // B-phase d-half partials
    __shared__ float esum_sh[D_];
    __shared__ int   idx_sh[L_];

    const int t    = threadIdx.x;
    const int lane = t & 63;
    const int wave = t >> 6;
    const int b    = blockIdx.x;

    if (t < L_) idx_sh[t] = item_seq[b * L_ + t];
    if (t >= 64 && t < 128) {
        const int uid = user_ids[b];
        u_sh[t - 64] = user_emb_table[(size_t)uid * D_ + (t - 64)];
    }
    __syncthreads();   // idx_sh / u_sh ready

    if (wave == 3) {
        // gbias[d] = fg_item_b + fg_user_b + u @ fg_user_W (coalesced, L1-hot)
        float g0 = fg_item_b[lane], g1 = fg_user_b[lane], g2 = 0.f, g3 = 0.f;
#pragma unroll
        for (int k = 0; k < D_; k += 4) {
            g0 = fmaf(u_sh[k + 0], fg_user_W[(k + 0) * D_ + lane], g0);
            g1 = fmaf(u_sh[k + 1], fg_user_W[(k + 1) * D_ + lane], g1);
            g2 = fmaf(u_sh[k + 2], fg_user_W[(k + 2) * D_ + lane], g2);
            g3 = fmaf(u_sh[k + 3], fg_user_W[(k + 3) * D_ + lane], g3);
        }
        gb_sh[lane] = (g0 + g1) + (g2 + g3);
    } else {
        // waves 0-2 (192 threads): stage E as bf16 (800 float4 gathers)
        for (int i = t; i < L_ * 16; i += 192) {
            const int l = i >> 4, qd = i & 15;
            const float4 r = ((const float4*)(item_emb_table + (size_t)idx_sh[l] * D_))[qd];
            ushort4v o = { f2bf(r.x), f2bf(r.y), f2bf(r.z), f2bf(r.w) };
            *(ushort4v*)&eb_sh[l * RS + qd * 4] = o;
        }
    }
    __syncthreads();   // eb / gb ready

    // ---- MFMA gate matmul + fused finalize. Wave w -> P rows [16w,16w+16).
    {
        const int m = lane & 15, q = lane >> 4;
        const int arow = 16 * wave + m;
        const short8 a0 = *(const short8*)&eb_sh[arow * RS + q * 8];       // k 0..31
        const short8 a1 = *(const short8*)&eb_sh[arow * RS + 32 + q * 8];  // k 32..63
#pragma unroll
        for (int n = 0; n < 4; ++n) {
            const int col = 16 * n + m;
            const short8 b0 = *(const short8*)&wbT[col * 64 + q * 8];      // global, L1-hot
            const short8 b1 = *(const short8*)&wbT[col * 64 + 32 + q * 8];
            float4v acc = {0.f, 0.f, 0.f, 0.f};
            acc = __builtin_amdgcn_mfma_f32_16x16x32_bf16(a0, b0, acc, 0, 0, 0);
            acc = __builtin_amdgcn_mfma_f32_16x16x32_bf16(a1, b1, acc, 0, 0, 0);
            const float gbc = gb_sh[col];
#pragma unroll
            for (int r = 0; r < 4; ++r) {
                const int l = 16 * wave + q * 4 + r;   // C/D: row=q*4+r, col=16n+m
                if (l < L_) {
                    const float e = bf2f(eb_sh[l * RS + col]);
                    part2_sh[l * SP2 + col] = f2bf(e * sigmoidf_(acc[r] + gbc));
                }
            }
        }
    }
    __syncthreads();   // gi ready

    // ---- Phase B partials (waves 0,1: d-halves) + esum (wave 2)
    if (wave < 2) {
        if (lane < L_) {
            const int d0 = 32 * wave;
            const unsigned short* prow = &part2_sh[lane * SP2];
            float p0 = 0.f, p1 = 0.f, p2 = 0.f, p3 = 0.f;
#pragma unroll
            for (int j = 0; j < 32; j += 4) {
                const int d = d0 + j;
                // packed bf16 pair -> two f32 via shift/mask (1 op each)
                const unsigned w01 = *(const unsigned*)&prow[d];
                const unsigned w23 = *(const unsigned*)&prow[d + 2];
                p0 = fmaf(__builtin_bit_cast(float, w01 << 16),          ig_item[d + 0], p0);
                p1 = fmaf(__builtin_bit_cast(float, w01 & 0xffff0000u),  ig_item[d + 1], p1);
                p2 = fmaf(__builtin_bit_cast(float, w23 << 16),          ig_item[d + 2], p2);
                p3 = fmaf(__builtin_bit_cast(float, w23 & 0xffff0000u),  ig_item[d + 3], p3);
                p0 = fmaf(u_sh[d + 0], ig_user[(d + 0) * L_ + lane], p0);
                p1 = fmaf(u_sh[d + 1], ig_user[(d + 1) * L_ + lane], p1);
                p2 = fmaf(u_sh[d + 2], ig_user[(d + 2) * L_ + lane], p2);
                p3 = fmaf(u_sh[d + 3], ig_user[(d + 3) * L_ + lane], p3);
            }
            bp_sh[wave][lane] = (p0 + p1) + (p2 + p3);
        }
    } else if (wave == 2) {            // esum[d] = sum_l e[l][d]
        float e0 = 0.f, e1 = 0.f;
#pragma unroll
        for (int l = 0; l < L_; l += 2) {
            e0 += bf2f(eb_sh[l * RS + lane]);
            e1 += bf2f(eb_sh[(l + 1) * RS + lane]);
        }
        esum_sh[lane] = e0 + e1;
    }
    __syncthreads();   // bp / esum ready

    // ---- Phase C: wave 0: s = sigmoid(bp0+bp1); v = u + union/ssum + esum
    if (wave == 0) {
        if (lane < L_) s_sh[lane] = sigmoidf_(bp_sh[0][lane] + bp_sh[1][lane]);
        // same-wave LDS dependency -> lgkmcnt, no barrier
        float a0 = 0.f, a1 = 0.f, ss = 0.f;
        for (int l = 0; l < L_; l += 2) {
            const float sA = s_sh[l], sB = s_sh[l + 1];
            a0 = fmaf(bf2f(part2_sh[l * SP2 + lane]), sA, a0);
            a1 = fmaf(bf2f(part2_sh[(l + 1) * SP2 + lane]), sB, a1);
            ss += sA + sB;
        }
        v_sh[lane] = u_sh[lane] + (a0 + a1) / ss + esum_sh[lane];
    }
    __syncthreads();   // v_sh ready

    // ---- Phase D: 2 threads per (b,t), half-row dots, combine via shfl
    if (t < 2 * T_) {
        const int tt = t >> 1, half = t & 1;
        const int idx = items_to_predict[b * T_ + tt];
        const float* wrow  = W2 + (size_t)idx * D_ + half * 32;
        const float* vhalf = v_sh + half * 32;
        float r0 = 0.f, r1 = 0.f, r2 = 0.f, r3 = 0.f;
#pragma unroll
        for (int kk = 0; kk < 8; ++kk) {
            const float4 w4 = ((const float4*)wrow)[kk];
            const float4 v4 = ((const float4*)vhalf)[kk];
            r0 = fmaf(v4.x, w4.x, r0);
            r1 = fmaf(v4.y, w4.y, r1);
            r2 = fmaf(v4.z, w4.z, r2);
            r3 = fmaf(v4.w, w4.w, r3);
        }
        float r = (r0 + r1) + (r2 + r3);
        r += __shfl_xor(r, 1, 64);
        if (half == 0) out[b * T_ + tt] = r + b2[idx];
    }
}

extern "C" void kernel_launch(void* const* d_in, const int* in_sizes, int n_in,
                              void* d_out, int out_size, void* d_ws, size_t ws_size,
                              hipStream_t stream) {
    const int*   item_seq   = (const int*)d_in[0];
    const int*   user_ids   = (const int*)d_in[1];
    const int*   items_pred = (const int*)d_in[2];
    const float* uet        = (const float*)d_in[3];
    const float* iet        = (const float*)d_in[4];
    const float* fgiW       = (const float*)d_in[5];
    const float* fgib       = (const float*)d_in[6];
    const float* fguW       = (const float*)d_in[7];
    const float* fgub       = (const float*)d_in[8];
    const float* igi        = (const float*)d_in[9];
    const float* igu        = (const float*)d_in[10];
    const float* W2         = (const float*)d_in[11];
    const float* b2t        = (const float*)d_in[12];

    unsigned short* wbT = (unsigned short*)d_ws;   // 8 KB bf16 W^T

    hgn_transpose_w<<<16, 256, 0, stream>>>(fgiW, wbT);
    hgn_fused_kernel<<<B_, 256, 0, stream>>>(
        item_seq, user_ids, items_pred, uet, iet,
        wbT, fgib, fguW, fgub, igi, igu, W2, b2t, (float*)d_out);
}